// Round 2
// baseline (275.470 us; speedup 1.0000x reference)
//
#include <hip/hip_runtime.h>
#include <math.h>

// BERT-CRF forward NLL on MI355X.
// Exp-domain forward recursion: alpha[b,j] = c[b]*ln2 + log(p[b,j]).
// Per step: q[j] = sum_i p[i]*E[i][j]  (E = exp(trans), column j in VGPRs),
// then p <- q * scale * exp(feat), c += k, where scale = 2^-k is derived from
// the PREVIOUS step's q[0] (one-step-stale renormalization: exact because k is
// accounted in c; staleness only shifts the centering by a bounded amount).
// This takes the renorm bpermute OFF the per-step critical chain.
// Lane j = tag j; one item per 32-lane half; 2 items per wave; block=64.
// Gold score fused, with its bpermute/LDS lookups issued off-chain.

constexpr int NTAG   = 32;
constexpr int TSTART = 30;
constexpr int TSTOP  = 31;
constexpr int NB     = 1024;
constexpr int NS     = 512;
constexpr int PD     = 8;   // prefetch depth

__global__ __launch_bounds__(64)
void crf_fwd(const float* __restrict__ feats,
             const int*   __restrict__ labels,
             const int*   __restrict__ lengths,
             const float* __restrict__ trans,
             float*       __restrict__ out)
{
    __shared__ __align__(16) float s_p[2][NTAG];   // per-half p vector
    __shared__ float s_trans[NTAG * NTAG];

    const int tid  = threadIdx.x;
    const int half = tid >> 5;
    const int j    = tid & 31;
    const int b    = (blockIdx.x << 1) + half;

    // stage trans into LDS (coalesced)
    for (int k = tid; k < NTAG * NTAG; k += 64)
        s_trans[k] = trans[k];

    // E column j: E[i][j] = exp(trans[i][j]); exp(-10000) -> 0 handles the
    // banned transitions (column START, row STOP) automatically.
    float Ecol[NTAG];
    #pragma unroll
    for (int i = 0; i < NTAG; ++i)
        Ecol[i] = __expf(trans[i * NTAG + j]);

    const int len = lengths[b];
    const float* fb = feats  + (size_t)b * NS * NTAG;
    const int*   lb = labels + (size_t)b * NS;

    // t = 0
    float feat0 = fb[j];
    int   lab0  = lb[0];

    __syncthreads();   // s_trans ready

    float a0 = feat0 + s_trans[TSTART * NTAG + j];
    float p  = __expf(a0);
    s_p[half][j] = p;

    int   c        = 0;
    float emit     = __shfl(feat0, lab0, 32);          // feats[b,0,labels[b,0]]
    float pairs    = 0.0f;
    float start_sc = s_trans[TSTART * NTAG + lab0];
    int   lab_prev = lab0;
    int   lab_last = lab0;

    const int wl = max(len, __shfl_xor(len, 32, 64));  // max over the wave's 2 items

    // Seed the (one-step-stale) renorm chain from p's lane 0.
    float seed = __shfl(p, 0, 32);
    {
        // nothing on the critical path yet
    }
    unsigned sbits = __float_as_uint(seed);
    int   sexpo = min(max((int)((sbits >> 23) & 0xFF), 40), 215);
    float scale = __uint_as_float((unsigned)(254 - sexpo) << 23); // 2^{127-expo}
    int   k     = sexpo - 127;

    // prefetch pipeline for feats/labels
    float pf[PD];
    int   pl[PD];
    #pragma unroll
    for (int d = 0; d < PD; ++d) {
        int tt = min(1 + d, NS - 1);
        pf[d] = fb[tt * NTAG + j];
        pl[d] = lb[tt];
    }

    const float4* pv4 = (const float4*)s_p[half];

    int t = 1;
    while (t < wl) {
        #pragma unroll
        for (int u = 0; u < PD; ++u) {
            if (t < wl) {   // wave-uniform predicate
                float feat = pf[u];
                int   lab  = pl[u];

                // ---- off-chain work, issued while LDS reads are in flight ----
                // gold-score lookups (independent of the recursion)
                float femit = __shfl(feat, lab, 32);          // feats[b,t,lab]
                float pr    = s_trans[lab_prev * NTAG + lab]; // trans[lab_{t-1},lab_t]
                // prefetch for step t+PD
                int tn = min(t + PD, NS - 1);
                pf[u] = fb[tn * NTAG + j];
                pl[u] = lb[tn];
                // emission factor and combined scale (scale is from step t-1)
                float F  = __expf(feat);
                float sf = scale * F;

                // keep compiler from moving LDS reads across the p store
                asm volatile("" ::: "memory");

                // ---- critical chain: q[j] = sum_i p[i] * E[i][j] ----
                float acc[4] = {0.f, 0.f, 0.f, 0.f};
                #pragma unroll
                for (int g = 0; g < 8; ++g) {
                    float4 pg = pv4[g];
                    float a = acc[g & 3];
                    a = fmaf(pg.x, Ecol[4 * g + 0], a);
                    a = fmaf(pg.y, Ecol[4 * g + 1], a);
                    a = fmaf(pg.z, Ecol[4 * g + 2], a);
                    a = fmaf(pg.w, Ecol[4 * g + 3], a);
                    acc[g & 3] = a;
                }
                float q  = (acc[0] + acc[1]) + (acc[2] + acc[3]);
                float pn = q * sf;

                bool upd = (t < len);
                p = upd ? pn : p;
                c = upd ? (c + k) : c;

                s_p[half][j] = p;

                // ---- off-chain: next step's renorm factor from THIS q ----
                float    q0   = __shfl(q, 0, 32);
                unsigned bits = __float_as_uint(q0);
                int      expo = (int)((bits >> 23) & 0xFF);
                expo  = min(max(expo, 40), 215);
                scale = __uint_as_float((unsigned)(254 - expo) << 23); // 2^-k
                k     = expo - 127;

                // gold-score accumulation (off-chain)
                emit     += upd ? femit : 0.f;
                pairs    += upd ? pr    : 0.f;
                lab_last  = upd ? lab   : lab_last;
                lab_prev  = lab;
            }
            ++t;
        }
    }

    // forward score = c*ln2 + log(sum_j p[j])
    float s = p;
    #pragma unroll
    for (int m = 16; m > 0; m >>= 1)
        s += __shfl_xor(s, m, 32);
    float fwd = (float)c * 0.69314718055994530942f + __logf(s);

    float stop_sc = s_trans[lab_last * NTAG + TSTOP];
    float gold    = emit + start_sc + pairs + stop_sc;

    if (j == 0)
        atomicAdd(out, (fwd - gold) * (1.0f / 1024.0f));
}

extern "C" void kernel_launch(void* const* d_in, const int* in_sizes, int n_in,
                              void* d_out, int out_size, void* d_ws, size_t ws_size,
                              hipStream_t stream) {
    const float* feats   = (const float*)d_in[0];
    const int*   labels  = (const int*)d_in[1];
    const int*   lengths = (const int*)d_in[2];
    const float* trans   = (const float*)d_in[3];
    float*       out     = (float*)d_out;

    hipMemsetAsync(out, 0, sizeof(float) * (size_t)out_size, stream);
    crf_fwd<<<dim3(NB / 2), dim3(64), 0, stream>>>(feats, labels, lengths, trans, out);
}

// Round 3
// 198.625 us; speedup vs baseline: 1.3869x; 1.3869x over previous
//
#include <hip/hip_runtime.h>
#include <math.h>

// BERT-CRF forward NLL on MI355X — register-only recursion, no LDS/DS on the
// critical path. One item per 64-lane wave, p duplicated mod 32 across halves.
// Matvec q[j] = sum_i p[i]*E[i][j] via DPP wave rotations:
//   chain A (wave_rol:1): offsets 0..15,  chain B (wave_ror:1): offsets 31..16.
// Renorm: p scaled by 2^-k, k = ilogb(p[0]) (exact, SALU bookkeeping in c).
// Gold score fused via v_readlane (emit) + scalar loads (pair/start/stop).

constexpr int NTAG = 32;
constexpr int TSTART = 30;
constexpr int TSTOP = 31;
constexpr int NB = 1024;
constexpr int NS = 512;

constexpr float LOG2E = 1.44269504088896340736f;
constexpr float LN2   = 0.69314718055994530942f;

__device__ __forceinline__ float rotl1(float x) {  // dst[i] = src[(i+1)%64]
    return __int_as_float(__builtin_amdgcn_update_dpp(
        0, __float_as_int(x), 0x134 /*wave_rol:1*/, 0xF, 0xF, false));
}
__device__ __forceinline__ float rotr1(float x) {  // dst[i] = src[(i-1)%64]
    return __int_as_float(__builtin_amdgcn_update_dpp(
        0, __float_as_int(x), 0x13C /*wave_ror:1*/, 0xF, 0xF, false));
}
__device__ __forceinline__ float fexp2(float x) {
#if __has_builtin(__builtin_amdgcn_exp2f)
    return __builtin_amdgcn_exp2f(x);
#else
    return exp2f(x);
#endif
}
__device__ __forceinline__ float rdlane(float v, int lane) {
    return __int_as_float(__builtin_amdgcn_readlane(__float_as_int(v), lane));
}

__global__ __launch_bounds__(64)
void crf_fwd(const float* __restrict__ feats,
             const int*   __restrict__ labels,
             const int*   __restrict__ lengths,
             const float* __restrict__ trans,
             float*       __restrict__ out)
{
    const int j   = threadIdx.x;   // 0..63
    const int j32 = j & 31;
    const int b   = blockIdx.x;

    // Per-lane E coefficients (exp of trans), indexed by rotation offset.
    // EA[r][lane j] = exp(trans[(j+r)&31][j&31])   r = 0..15   (rol chain)
    // EB[s][lane j] = exp(trans[(j-s)&31][j&31])   s = 1..16   (ror chain)
    float EA[16], EB[16];
    #pragma unroll
    for (int r = 0; r < 16; ++r)
        EA[r] = fexp2(trans[(((j32 + r) & 31) << 5) + j32] * LOG2E);
    #pragma unroll
    for (int s = 1; s <= 16; ++s)
        EB[s - 1] = fexp2(trans[(((j32 - s) & 31) << 5) + j32] * LOG2E);

    const int len = lengths[b];
    const float* fb = feats  + (size_t)b * NS * NTAG;
    const int*   lb = labels + (size_t)b * NS;

    // t = 0
    float feat0 = fb[j32];
    int   lab0  = lb[0];
    float p = fexp2((feat0 + trans[(TSTART << 5) + j32]) * LOG2E);
    float gacc = rdlane(feat0, lab0) + trans[(TSTART << 5) + lab0];
    int lab_prev = lab0;

    int bits0 = __builtin_amdgcn_readfirstlane(__float_as_int(p));
    int e0    = min(max((bits0 >> 23) & 0xFF, 1), 254);
    int kreg  = e0 - 127;
    int creg  = 0;

    // feats prefetch pipeline (8 deep)
    float pf[8];
    #pragma unroll
    for (int u = 0; u < 8; ++u) {
        int tt = min(1 + u, NS - 1);
        pf[u] = fb[(size_t)tt * NTAG + j32];
    }

    const int nsteps = len - 1;        // recursion steps t = 1..len-1
    const int nchunk = nsteps >> 3;
    const int rem    = nsteps & 7;
    int t = 1;

    #define CRF_STEP(FEAT, LAB)                                              \
    {                                                                        \
        float feat_ = (FEAT);                                                \
        int   lab_  = (LAB);                                                 \
        /* off-chain: emission factor with folded 2^-k */                    \
        creg += kreg;                                                        \
        float kf = (float)kreg;                                              \
        float F  = fexp2(fmaf(feat_, LOG2E, -kf));                           \
        /* off-chain: gold-score terms (uniform scalars) */                  \
        gacc += rdlane(feat_, lab_);                                         \
        gacc += trans[(lab_prev << 5) + lab_];                               \
        lab_prev = lab_;                                                     \
        /* critical chain: two DPP rotation chains */                        \
        float R = p, L = p;                                                  \
        float accA = p * EA[0];                                              \
        R = rotl1(R); accA = fmaf(R, EA[1], accA);                           \
        float accB;                                                          \
        L = rotr1(L); accB = L * EB[0];                                      \
        _Pragma("unroll")                                                    \
        for (int r_ = 2; r_ < 16; ++r_) {                                    \
            R = rotl1(R); accA = fmaf(R, EA[r_], accA);                      \
        }                                                                    \
        _Pragma("unroll")                                                    \
        for (int s_ = 2; s_ <= 16; ++s_) {                                   \
            L = rotr1(L); accB = fmaf(L, EB[s_ - 1], accB);                  \
        }                                                                    \
        float q = accA + accB;                                               \
        p = q * F;                                                           \
        /* renorm bookkeeping for next step (off next chain) */              \
        int bits_ = __builtin_amdgcn_readfirstlane(__float_as_int(p));       \
        int e_ = min(max((bits_ >> 23) & 0xFF, 1), 254);                     \
        kreg = e_ - 127;                                                     \
    }

    for (int ci = 0; ci < nchunk; ++ci) {
        #pragma unroll
        for (int u = 0; u < 8; ++u) {
            float feat = pf[u];
            int   lab  = lb[t];                        // uniform -> s_load
            int   tp   = min(t + 8, NS - 1);
            pf[u] = fb[(size_t)tp * NTAG + j32];       // prefetch t+8
            CRF_STEP(feat, lab)
            ++t;
        }
    }
    // remainder (<8 steps); pf[u] holds feats for t = 1+8*nchunk+u
    #pragma unroll
    for (int u = 0; u < 7; ++u) {
        if (u < rem) {
            float feat = pf[u];
            int   lab  = lb[t];
            CRF_STEP(feat, lab)
            ++t;
        }
    }
    #undef CRF_STEP

    // forward score = c*ln2 + log(sum_j p[j]); p duplicated mod 32, so a
    // 5-stage xor butterfly over masks 1..16 sums the 32 distinct entries.
    float s = p;
    #pragma unroll
    for (int m = 1; m <= 16; m <<= 1)
        s += __shfl_xor(s, m, 64);
    float fwd = (float)creg * LN2 + logf(s);

    // gold score: add stop transition
    gacc += trans[(lab_prev << 5) + TSTOP];

    if (j == 0)
        atomicAdd(out, (fwd - gacc) * (1.0f / 1024.0f));
}

extern "C" void kernel_launch(void* const* d_in, const int* in_sizes, int n_in,
                              void* d_out, int out_size, void* d_ws, size_t ws_size,
                              hipStream_t stream) {
    const float* feats   = (const float*)d_in[0];
    const int*   labels  = (const int*)d_in[1];
    const int*   lengths = (const int*)d_in[2];
    const float* trans   = (const float*)d_in[3];
    float*       out     = (float*)d_out;

    hipMemsetAsync(out, 0, sizeof(float) * (size_t)out_size, stream);
    crf_fwd<<<dim3(NB), dim3(64), 0, stream>>>(feats, labels, lengths, trans, out);
}

// Round 4
// 177.868 us; speedup vs baseline: 1.5487x; 1.1167x over previous
//
#include <hip/hip_runtime.h>
#include <math.h>

// BERT-CRF forward NLL on MI355X — register-only serial recursion, with ALL
// gold-score work moved OUT of the serial loop (it was stalling each step on
// SMEM latency for labels/trans lookups). One item per 64-lane wave, p
// duplicated mod 32 across halves. Matvec via two DPP wave-rotation chains.
// Gold score computed as a parallel gather tail after the recursion.

constexpr int NTAG = 32;
constexpr int TSTART = 30;
constexpr int TSTOP = 31;
constexpr int NB = 1024;
constexpr int NS = 512;

constexpr float LOG2E = 1.44269504088896340736f;
constexpr float LN2   = 0.69314718055994530942f;

__device__ __forceinline__ float rotl1(float x) {  // dst[i] = src[(i+1)%64]
    return __int_as_float(__builtin_amdgcn_update_dpp(
        0, __float_as_int(x), 0x134 /*wave_rol:1*/, 0xF, 0xF, false));
}
__device__ __forceinline__ float rotr1(float x) {  // dst[i] = src[(i-1)%64]
    return __int_as_float(__builtin_amdgcn_update_dpp(
        0, __float_as_int(x), 0x13C /*wave_ror:1*/, 0xF, 0xF, false));
}
__device__ __forceinline__ float fexp2(float x) {
#if __has_builtin(__builtin_amdgcn_exp2f)
    return __builtin_amdgcn_exp2f(x);
#else
    return exp2f(x);
#endif
}

__global__ __launch_bounds__(64)
void crf_fwd(const float* __restrict__ feats,
             const int*   __restrict__ labels,
             const int*   __restrict__ lengths,
             const float* __restrict__ trans,
             float*       __restrict__ out)
{
    const int j   = threadIdx.x;   // 0..63
    const int j32 = j & 31;
    const int b   = blockIdx.x;

    // Per-lane E coefficients (exp of trans), indexed by rotation offset.
    // EA[r][lane j] = exp(trans[(j+r)&31][j&31])   r = 0..15   (rol chain)
    // EB[s][lane j] = exp(trans[(j-s)&31][j&31])   s = 1..16   (ror chain)
    float EA[16], EB[16];
    #pragma unroll
    for (int r = 0; r < 16; ++r)
        EA[r] = fexp2(trans[(((j32 + r) & 31) << 5) + j32] * LOG2E);
    #pragma unroll
    for (int s = 1; s <= 16; ++s)
        EB[s - 1] = fexp2(trans[(((j32 - s) & 31) << 5) + j32] * LOG2E);

    const int len = lengths[b];
    const float* fb = feats  + (size_t)b * NS * NTAG;
    const int*   lb = labels + (size_t)b * NS;

    // labels for this item, staged into registers (coalesced, off the loop)
    int labr[8];
    #pragma unroll
    for (int k = 0; k < 8; ++k)
        labr[k] = lb[(k << 6) + j];

    // t = 0
    float feat0 = fb[j32];
    float p = fexp2((feat0 + trans[(TSTART << 5) + j32]) * LOG2E);

    int bits0 = __builtin_amdgcn_readfirstlane(__float_as_int(p));
    int e0    = min(max((bits0 >> 23) & 0xFF, 1), 254);
    int kreg  = e0 - 127;
    int creg  = 0;

    // feats prefetch pipeline (8 deep)
    float pf[8];
    #pragma unroll
    for (int u = 0; u < 8; ++u) {
        int tt = min(1 + u, NS - 1);
        pf[u] = fb[(size_t)tt * NTAG + j32];
    }

    const int nsteps = len - 1;        // recursion steps t = 1..len-1
    const int nchunk = nsteps >> 3;
    const int rem    = nsteps & 7;
    int t = 1;

    #define CRF_STEP(FEAT)                                                   \
    {                                                                        \
        float feat_ = (FEAT);                                                \
        /* off-chain: emission factor with folded 2^-k */                    \
        creg += kreg;                                                        \
        float kf = (float)kreg;                                              \
        float F  = fexp2(fmaf(feat_, LOG2E, -kf));                           \
        /* critical chain: two DPP rotation chains */                        \
        float R = p, L = p;                                                  \
        float accA = p * EA[0];                                              \
        R = rotl1(R); accA = fmaf(R, EA[1], accA);                           \
        float accB;                                                          \
        L = rotr1(L); accB = L * EB[0];                                      \
        _Pragma("unroll")                                                    \
        for (int r_ = 2; r_ < 16; ++r_) {                                    \
            R = rotl1(R); accA = fmaf(R, EA[r_], accA);                      \
        }                                                                    \
        _Pragma("unroll")                                                    \
        for (int s_ = 2; s_ <= 16; ++s_) {                                   \
            L = rotr1(L); accB = fmaf(L, EB[s_ - 1], accB);                  \
        }                                                                    \
        float q = accA + accB;                                               \
        p = q * F;                                                           \
        /* renorm bookkeeping for next step (off next chain) */              \
        int bits_ = __builtin_amdgcn_readfirstlane(__float_as_int(p));       \
        int e_ = min(max((bits_ >> 23) & 0xFF, 1), 254);                     \
        kreg = e_ - 127;                                                     \
    }

    for (int ci = 0; ci < nchunk; ++ci) {
        #pragma unroll
        for (int u = 0; u < 8; ++u) {
            float feat = pf[u];
            int   tp   = min(t + 8, NS - 1);
            pf[u] = fb[(size_t)tp * NTAG + j32];       // prefetch t+8
            CRF_STEP(feat)
            ++t;
        }
    }
    // remainder (<8 steps); pf[u] holds feats for t = 1+8*nchunk+u
    #pragma unroll
    for (int u = 0; u < 7; ++u) {
        if (u < rem) {
            CRF_STEP(pf[u])
            ++t;
        }
    }
    #undef CRF_STEP

    // forward score = c*ln2 + log(sum_j p[j]); p duplicated mod 32, so the
    // xor butterfly over masks 1..16 sums the 32 distinct entries.
    float s = p;
    #pragma unroll
    for (int m = 1; m <= 16; m <<= 1)
        s += __shfl_xor(s, m, 64);
    float fwd = (float)creg * LN2 + logf(s);

    // ---- gold score: parallel gather tail (latency-tolerant) ----
    float gold = 0.0f;
    #pragma unroll
    for (int k = 0; k < 8; ++k) {
        int tt = (k << 6) + j;
        if (tt < len) {
            int lab_t = labr[k];
            gold += fb[(size_t)tt * NTAG + lab_t];               // emit
            if (tt > 0)
                gold += trans[(lb[tt - 1] << 5) + lab_t];        // pair
            else
                gold += trans[(TSTART << 5) + lab_t];            // start
            if (tt == len - 1)
                gold += trans[(lab_t << 5) + TSTOP];             // stop
        }
    }
    // reduce gold over all 64 lanes (each (b,t) counted once)
    #pragma unroll
    for (int m = 1; m <= 32; m <<= 1)
        gold += __shfl_xor(gold, m, 64);

    if (j == 0)
        atomicAdd(out, (fwd - gold) * (1.0f / 1024.0f));
}

extern "C" void kernel_launch(void* const* d_in, const int* in_sizes, int n_in,
                              void* d_out, int out_size, void* d_ws, size_t ws_size,
                              hipStream_t stream) {
    const float* feats   = (const float*)d_in[0];
    const int*   labels  = (const int*)d_in[1];
    const int*   lengths = (const int*)d_in[2];
    const float* trans   = (const float*)d_in[3];
    float*       out     = (float*)d_out;

    hipMemsetAsync(out, 0, sizeof(float) * (size_t)out_size, stream);
    crf_fwd<<<dim3(NB), dim3(64), 0, stream>>>(feats, labels, lengths, trans, out);
}